// Round 1
// 1020.933 us; speedup vs baseline: 1.0159x; 1.0159x over previous
//
#include <hip/hip_runtime.h>

#define B_    2
#define L_    1024
#define D_    768
#define H_    12
#define DH_   64
#define DP_   32
#define MLP_  3072
#define NL_   4
#define WIN_  128
#define W2_   257            // window columns (rel = j-i+128 in [0,256])
#define M_    (B_*L_)        // 2048 rows

typedef __attribute__((ext_vector_type(8))) short bf16x8;
typedef __attribute__((ext_vector_type(4))) float f32x4;

__device__ __forceinline__ unsigned short f2bf(float x){
  unsigned int u = __float_as_uint(x);
  u += 0x7fffu + ((u >> 16) & 1u);   // RNE; inputs finite
  return (unsigned short)(u >> 16);
}

__device__ __forceinline__ void gl_lds16(const void* g, void* l){
  __builtin_amdgcn_global_load_lds((__attribute__((address_space(1))) void*)g,
                                   (__attribute__((address_space(3))) void*)l, 16, 0, 0);
}

// ---------------- f32 -> bf16 weight conversion ----------------
__global__ __launch_bounds__(256) void cvt_bf16_k(const float* __restrict__ src,
                                                  unsigned short* __restrict__ dst, int n4){
  int i = blockIdx.x*256 + threadIdx.x;
  if (i >= n4) return;
  float4 v = ((const float4*)src)[i];
  ushort4 o;
  o.x = f2bf(v.x); o.y = f2bf(v.y); o.z = f2bf(v.z); o.w = f2bf(v.w);
  ((ushort4*)dst)[i] = o;
}

// ---------------- pair bias: LN(pair)@pb_w + pb_b for ALL layers, window only ----
__global__ __launch_bounds__(256) void pair_bias_k(const float* __restrict__ pair,
    const float* __restrict__ ln_g, const float* __restrict__ ln_b,
    const float* __restrict__ pb_w, const float* __restrict__ pb_b,
    float* __restrict__ bias){
  __shared__ float gw[NL_][DP_];
  __shared__ float cb[NL_];
  int tid = threadIdx.x;
  if (tid < NL_*DP_) gw[tid>>5][tid&31] = ln_g[tid]*pb_w[tid];
  if (tid < NL_){
    float c = 0.f;
    for (int d=0; d<DP_; ++d) c += ln_b[tid*DP_+d]*pb_w[tid*DP_+d];
    cb[tid] = c + pb_b[tid];
  }
  __syncthreads();
  int idx = blockIdx.x*256 + tid;
  if (idx >= B_*L_*W2_) return;
  int rel = idx % W2_;
  int t   = idx / W2_;
  int i   = t & (L_-1);
  int b   = t >> 10;
  int j   = i + rel - WIN_;
  if (j < 0 || j >= L_) return;            // never read by attention
  const float4* p = (const float4*)(pair + ((size_t)(b*L_ + i)*L_ + j)*DP_);
  float4 x[8];
  #pragma unroll
  for (int q=0;q<8;++q) x[q] = p[q];
  float s=0.f, ss=0.f;
  #pragma unroll
  for (int q=0;q<8;++q){
    s  += x[q].x + x[q].y + x[q].z + x[q].w;
    ss += x[q].x*x[q].x + x[q].y*x[q].y + x[q].z*x[q].z + x[q].w*x[q].w;
  }
  float m  = s * (1.0f/DP_);
  float rs = rsqrtf(ss*(1.0f/DP_) - m*m + 1e-5f);
  #pragma unroll
  for (int l=0;l<NL_;++l){
    float acc = 0.f;
    #pragma unroll
    for (int q=0;q<8;++q){
      acc += (x[q].x-m)*gw[l][4*q+0] + (x[q].y-m)*gw[l][4*q+1]
           + (x[q].z-m)*gw[l][4*q+2] + (x[q].w-m)*gw[l][4*q+3];
    }
    bias[(((size_t)l*B_ + b)*L_ + i)*W2_ + rel] = acc*rs + cb[l];
  }
}

// ---------------- rmsnorm: s[M,768] f32 -> h bf16 ----------------
__global__ __launch_bounds__(256) void rmsnorm_k(const float* __restrict__ s,
                                                 unsigned short* __restrict__ h){
  int row = blockIdx.x, tid = threadIdx.x;
  const float* x = s + (size_t)row*D_;
  float v0 = x[tid], v1 = x[tid+256], v2 = x[tid+512];
  float ss = v0*v0 + v1*v1 + v2*v2;
  #pragma unroll
  for (int m=1; m<64; m<<=1) ss += __shfl_xor(ss, m, 64);
  __shared__ float wsum[4];
  __shared__ float rbuf;
  if ((tid & 63) == 0) wsum[tid>>6] = ss;
  __syncthreads();
  if (tid == 0) rbuf = rsqrtf((wsum[0]+wsum[1]+wsum[2]+wsum[3])*(1.0f/D_) + 1.1920929e-07f);
  __syncthreads();
  float r = rbuf;
  unsigned short* o = h + (size_t)row*D_;
  o[tid]     = f2bf(v0*r);
  o[tid+256] = f2bf(v1*r);
  o[tid+512] = f2bf(v2*r);
}

// ---------------- bf16 GEMM: C[M,N] = A[M,K] @ W[N,K]^T + bias, fused epilogues ----
// MODE 0: outf = C for q/k cols; v cols -> outb bf16 in [bh][j][64] layout (qkv)
// MODE 1: resid += C          (attn out proj)
// MODE 2: outb = bf16(gelu(C))(fc1)
// MODE 3: resid += C          (fc2)
// TM: 128 or 64 (M rows per block). SPLIT: split-K factor (atomicAdd epilogue if >1).
template<int MODE, int TM, int SPLIT>
__global__ __launch_bounds__(256) void gemm_bt(const unsigned short* __restrict__ A,
    const unsigned short* __restrict__ W, const float* __restrict__ bias,
    float* __restrict__ outf, unsigned short* __restrict__ outb,
    float* __restrict__ resid, int N, int K){
  constexpr int MI = TM/32;
  __shared__ __align__(16) short sm[2][(TM+128)*32];
  const int tid  = threadIdx.x;
  const int wave = tid >> 6, lane = tid & 63;
  const int m0 = blockIdx.y*TM, n0 = blockIdx.x << 7;
  const int KB = K / SPLIT;
  const int kbase = blockIdx.z * KB;
  const int wm = (wave >> 1)*(TM/2), wn = (wave & 1) << 6;
  const int lrow = lane & 15, ko = (lane >> 4) << 3;
  f32x4 acc[MI][4] = {};
  const unsigned short* Ag = A + (size_t)(m0 + (tid>>2))*K + kbase + ((tid&3)<<3);
  const unsigned short* Wg = W + (size_t)(n0 + (tid>>2))*K + kbase + ((tid&3)<<3);
  const size_t hstep = (size_t)64*K;
  const int nk = KB >> 5;
  {  // prologue stage into buf 0
    short* As = sm[0]; short* Bs = sm[0] + TM*32;
    gl_lds16(Ag, &As[tid*8]);
    if (TM == 128) gl_lds16(Ag + hstep, &As[(tid+256)*8]);
    gl_lds16(Wg, &Bs[tid*8]);
    gl_lds16(Wg + hstep, &Bs[(tid+256)*8]);
  }
  for (int it = 0; it < nk; ++it){
    __syncthreads();                       // drains vmcnt -> buf (it&1) ready
    if (it + 1 < nk){                      // async-prefetch next tile, overlaps MFMA below
      short* As = sm[(it&1)^1]; short* Bs = As + TM*32;
      const int kt = (it+1) << 5;
      gl_lds16(Ag + kt, &As[tid*8]);
      if (TM == 128) gl_lds16(Ag + hstep + kt, &As[(tid+256)*8]);
      gl_lds16(Wg + kt, &Bs[tid*8]);
      gl_lds16(Wg + hstep + kt, &Bs[(tid+256)*8]);
    }
    const short* As = sm[it&1]; const short* Bs = As + TM*32;
    bf16x8 af[MI], bv[4];
    #pragma unroll
    for (int i=0;i<MI;++i) af[i] = *(const bf16x8*)&As[((wm + i*16 + lrow) << 5) + ko];
    #pragma unroll
    for (int i=0;i<4;++i)  bv[i] = *(const bf16x8*)&Bs[((wn + i*16 + lrow) << 5) + ko];
    #pragma unroll
    for (int mi=0;mi<MI;++mi)
      #pragma unroll
      for (int ni=0;ni<4;++ni)
        acc[mi][ni] = __builtin_amdgcn_mfma_f32_16x16x32_bf16(af[mi], bv[ni], acc[mi][ni], 0, 0, 0);
  }
  #pragma unroll
  for (int ni=0;ni<4;++ni){
    const int col = n0 + wn + ni*16 + lrow;
    const float bb = (SPLIT == 1 || blockIdx.z == 0) ? bias[col] : 0.f;
    #pragma unroll
    for (int mi=0;mi<MI;++mi){
      const int rw = m0 + wm + mi*16 + ((lane >> 4) << 2);
      #pragma unroll
      for (int r=0;r<4;++r){
        float v = acc[mi][ni][r] + bb;
        if (MODE == 0){
          if (col < 2*D_){
            outf[(size_t)(rw + r)*N + col] = v;
          } else {
            const int rowg = rw + r;
            const int bI = rowg >> 10, jI = rowg & (L_-1);
            const int hI = (col - 2*D_) >> 6;
            outb[(((size_t)(bI*H_ + hI)*L_ + jI) << 6) + (col & 63)] = f2bf(v);
          }
        } else if (MODE == 2){
          float g = 0.5f * v * (1.0f + erff(v * 0.70710678118654752f));
          outb[(size_t)(rw + r)*N + col] = f2bf(g);
        } else {
          if (SPLIT == 1) resid[(size_t)(rw + r)*D_ + col] += v;
          else            atomicAdd(&resid[(size_t)(rw + r)*D_ + col], v);
        }
      }
    }
  }
}

// ---------------- rope: qkv f32 [M,2304] -> q_r,k_r [B*H, L, 64] bf16 ----
__global__ __launch_bounds__(256) void rope_k(const float* __restrict__ qkv,
    unsigned short* __restrict__ qr, unsigned short* __restrict__ kr){
  int idx = blockIdx.x*256 + threadIdx.x;
  int d  = idx & 63;
  int r  = idx >> 6;
  int i  = r & (L_-1);
  int bh = r >> 10;
  int b  = bh / H_, h = bh - (bh / H_)*H_;
  const float* base = qkv + ((size_t)(b*L_ + i))*(3*D_) + h*64 + d;
  float qv = base[0], kv = base[D_];
  int t = d & 31;
  float invf = expf(-(float)t * 0.28782313662425572f);   // ln(10000)/32
  float ang = (float)i * invf;
  float sn, cs;
  sincosf(ang, &sn, &cs);
  float pq = (d < 32) ? -base[32]    : base[-32];
  float pk = (d < 32) ? -base[D_+32] : base[D_-32];
  qr[idx] = f2bf(qv*cs + pq*sn);
  kr[idx] = f2bf(kv*cs + pk*sn);
}

// ---------------- windowed MFMA attention, 32-query tiles ----------------
// Per block: one (bh, 32-query tile). K-strip of 288 keys staged bf16 in LDS
// directly from precomputed bf16 K (no conversion), QK^T and PV via 16x16x32
// bf16 MFMA. V (precomputed bf16) reuses the K buffer after softmax.
__global__ __launch_bounds__(256) void attn_k(const unsigned short* __restrict__ qr,
    const unsigned short* __restrict__ kr, const unsigned short* __restrict__ vr,
    const float* __restrict__ bias, unsigned short* __restrict__ ybf, int layer){
  __shared__ __align__(16) short kb[288*72];   // K then V, row stride 72 (+8 pad) = 41472 B
  __shared__ __align__(16) float sc[32*304];   // scores f32 (38912 B); probs bf16 alias below
  short* ps = (short*)sc;                      // [32][296] bf16 (stride 296: conflict-free b128)
  const int tid  = threadIdx.x;
  const int wave = tid >> 6, lane = tid & 63;
  const int quad = lane >> 4, lrow = lane & 15;
  const int bh = blockIdx.y, b = bh / H_, h = bh - b*H_;
  const int i0 = blockIdx.x * 32, jb = i0 - WIN_;

  // Q fragments for both 16-row m-tiles: A[m=lrow][k=quad*8+j], two K=32 halves
  bf16x8 qf[2][2];
  #pragma unroll
  for (int mt=0; mt<2; ++mt){
    const unsigned short* qrow = qr + (((size_t)bh*L_ + i0 + mt*16 + lrow) << 6) + quad*8;
    qf[mt][0] = *(const bf16x8*)qrow;
    qf[mt][1] = *(const bf16x8*)(qrow + 32);
  }
  // stage K strip (288 rows x 64 bf16), zero-filled outside [0,L)
  {
    const int r0 = tid >> 3, seg = tid & 7;
    #pragma unroll
    for (int p=0; p<9; ++p){
      const int r = r0 + p*32;
      const int jg = jb + r;
      bf16x8 z;
      #pragma unroll
      for (int q=0;q<8;++q) z[q] = 0;
      if ((unsigned)jg < L_) z = *(const bf16x8*)(kr + (((size_t)bh*L_ + jg) << 6) + seg*8);
      *(bf16x8*)&kb[r*72 + seg*8] = z;
    }
  }
  __syncthreads();
  // QK^T: 18 key-chunks of 16, round-robin over waves; each wave does both m-tiles
  for (int c = wave; c < 18; c += 4){
    const int krow = c*16 + lrow;
    const bf16x8 kf0 = *(const bf16x8*)&kb[krow*72 + quad*8];
    const bf16x8 kf1 = *(const bf16x8*)&kb[krow*72 + 32 + quad*8];
    const int jj = c*16 + lrow, jg = jb + jj;
    #pragma unroll
    for (int mt=0; mt<2; ++mt){
      f32x4 cc = {0.f,0.f,0.f,0.f};
      cc = __builtin_amdgcn_mfma_f32_16x16x32_bf16(qf[mt][0], kf0, cc, 0, 0, 0);
      cc = __builtin_amdgcn_mfma_f32_16x16x32_bf16(qf[mt][1], kf1, cc, 0, 0, 0);
      #pragma unroll
      for (int r=0;r<4;++r){
        const int row = mt*16 + quad*4 + r;
        const int rel = jj - row;             // j - i + 128
        float v = -1e30f;
        if (rel >= 0 && rel <= 256 && (unsigned)jg < L_)
          v = cc[r]*0.125f + bias[(((size_t)(layer*B_ + b))*L_ + i0 + row)*W2_ + rel];
        sc[row*304 + jj] = v;
      }
    }
  }
  __syncthreads();
  // softmax: thread group of 16 handles rows qq and qq+16
  const int qq = tid >> 4, tj = tid & 15;
  float ev[2][18];
  #pragma unroll
  for (int g=0; g<2; ++g)
    #pragma unroll
    for (int c=0;c<18;++c) ev[g][c] = sc[(qq + g*16)*304 + c*16 + tj];
  __syncthreads();                 // all sc reads done before ps alias-writes
  #pragma unroll
  for (int g=0; g<2; ++g){
    float mx = -3.0e38f;
    #pragma unroll
    for (int c=0;c<18;++c) mx = fmaxf(mx, ev[g][c]);
    #pragma unroll
    for (int m=1; m<16; m<<=1) mx = fmaxf(mx, __shfl_xor(mx, m, 16));
    float sm = 0.f;
    #pragma unroll
    for (int c=0;c<18;++c){ float e = __expf(ev[g][c] - mx); ev[g][c] = e; sm += e; }
    #pragma unroll
    for (int m=1; m<16; m<<=1) sm += __shfl_xor(sm, m, 16);
    const float inv = 1.0f / sm;
    #pragma unroll
    for (int c=0;c<18;++c) ps[(qq + g*16)*296 + c*16 + tj] = (short)f2bf(ev[g][c]*inv);
  }
  // stage V into kb (zero-fill: ps~0 rows must not meet inf/NaN)
  {
    const int r0 = tid >> 3, seg = tid & 7;
    #pragma unroll
    for (int p=0; p<9; ++p){
      const int r = r0 + p*32;
      const int jg = jb + r;
      bf16x8 z;
      #pragma unroll
      for (int q=0;q<8;++q) z[q] = 0;
      if ((unsigned)jg < L_) z = *(const bf16x8*)(vr + (((size_t)bh*L_ + jg) << 6) + seg*8);
      *(bf16x8*)&kb[r*72 + seg*8] = z;
    }
  }
  __syncthreads();
  // PV: O[32][64] = P[32x288] @ V[288x64]; wave owns d-tile [wave*16, wave*16+16)
  f32x4 o0 = {0.f,0.f,0.f,0.f}, o1 = {0.f,0.f,0.f,0.f};
  for (int kc=0; kc<9; ++kc){
    bf16x8 bf;
    #pragma unroll
    for (int j=0;j<8;++j) bf[j] = kb[(kc*32 + quad*8 + j)*72 + wave*16 + lrow];
    const bf16x8 a0 = *(const bf16x8*)&ps[lrow*296 + kc*32 + quad*8];
    const bf16x8 a1 = *(const bf16x8*)&ps[(16 + lrow)*296 + kc*32 + quad*8];
    o0 = __builtin_amdgcn_mfma_f32_16x16x32_bf16(a0, bf, o0, 0, 0, 0);
    o1 = __builtin_amdgcn_mfma_f32_16x16x32_bf16(a1, bf, o1, 0, 0, 0);
  }
  #pragma unroll
  for (int r=0;r<4;++r){
    const int row = quad*4 + r;
    ybf[((size_t)(b*L_ + i0 + row))*D_ + h*64 + wave*16 + lrow]      = f2bf(o0[r]);
    ybf[((size_t)(b*L_ + i0 + 16 + row))*D_ + h*64 + wave*16 + lrow] = f2bf(o1[r]);
  }
}

extern "C" void kernel_launch(void* const* d_in, const int* in_sizes, int n_in,
                              void* d_out, int out_size, void* d_ws, size_t ws_size,
                              hipStream_t stream){
  (void)in_sizes; (void)n_in; (void)out_size; (void)ws_size;
  const float* s_in  = (const float*)d_in[0];
  const float* pair  = (const float*)d_in[1];
  const float* qkv_w = (const float*)d_in[2];
  const float* qkv_b = (const float*)d_in[3];
  const float* out_w = (const float*)d_in[4];
  const float* out_b = (const float*)d_in[5];
  const float* fc1_w = (const float*)d_in[6];
  const float* fc1_b = (const float*)d_in[7];
  const float* fc2_w = (const float*)d_in[8];
  const float* fc2_b = (const float*)d_in[9];
  const float* ln_g  = (const float*)d_in[10];
  const float* ln_b  = (const float*)d_in[11];
  const float* pb_w  = (const float*)d_in[12];
  const float* pb_b  = (const float*)d_in[13];
  float* s = (float*)d_out;                    // residual stream lives in d_out

  char* ws = (char*)d_ws;
  size_t off = 0;
  auto take = [&](size_t bytes)->char*{
    char* p = ws + off; off += (bytes + 255) & ~(size_t)255; return p;
  };
  unsigned short* wqkv = (unsigned short*)take((size_t)NL_*3*D_*D_*2);
  unsigned short* wout = (unsigned short*)take((size_t)NL_*D_*D_*2);
  unsigned short* wfc1 = (unsigned short*)take((size_t)NL_*MLP_*D_*2);
  unsigned short* wfc2 = (unsigned short*)take((size_t)NL_*D_*MLP_*2);
  float*          bw   = (float*)take((size_t)NL_*B_*L_*W2_*4);
  unsigned short* hbf  = (unsigned short*)take((size_t)M_*D_*2);
  float*          qkvf = (float*)take((size_t)M_*3*D_*4);
  unsigned short* qrb  = (unsigned short*)take((size_t)B_*H_*L_*DH_*2);
  unsigned short* krb  = (unsigned short*)take((size_t)B_*H_*L_*DH_*2);
  unsigned short* vrb  = (unsigned short*)take((size_t)B_*H_*L_*DH_*2);
  unsigned short* ybf  = (unsigned short*)take((size_t)M_*D_*2);
  unsigned short* gbf  = (unsigned short*)take((size_t)M_*MLP_*2);

  hipMemcpyAsync(s, s_in, (size_t)M_*D_*sizeof(float), hipMemcpyDeviceToDevice, stream);

  auto cvt = [&](const float* src, unsigned short* dst, size_t n){
    int n4 = (int)(n/4);
    cvt_bf16_k<<<(n4+255)/256, 256, 0, stream>>>(src, dst, n4);
  };
  cvt(qkv_w, wqkv, (size_t)NL_*3*D_*D_);
  cvt(out_w, wout, (size_t)NL_*D_*D_);
  cvt(fc1_w, wfc1, (size_t)NL_*MLP_*D_);
  cvt(fc2_w, wfc2, (size_t)NL_*D_*MLP_);

  pair_bias_k<<<(B_*L_*W2_ + 255)/256, 256, 0, stream>>>(pair, ln_g, ln_b, pb_w, pb_b, bw);

  for (int l=0; l<NL_; ++l){
    rmsnorm_k<<<M_, 256, 0, stream>>>(s, hbf);
    gemm_bt<0,128,1><<<dim3((3*D_)/128, M_/128), 256, 0, stream>>>(
        hbf, wqkv + (size_t)l*3*D_*D_, qkv_b + l*3*D_, qkvf, vrb, nullptr, 3*D_, D_);
    rope_k<<<(B_*H_*L_*DH_)/256, 256, 0, stream>>>(qkvf, qrb, krb);
    attn_k<<<dim3(L_/32, B_*H_), 256, 0, stream>>>(qrb, krb, vrb, bw, ybf, l);
    gemm_bt<1,64,2><<<dim3(D_/128, M_/64, 2), 256, 0, stream>>>(
        ybf, wout + (size_t)l*D_*D_, out_b + l*D_, nullptr, nullptr, s, D_, D_);
    rmsnorm_k<<<M_, 256, 0, stream>>>(s, hbf);
    gemm_bt<2,128,1><<<dim3(MLP_/128, M_/128), 256, 0, stream>>>(
        hbf, wfc1 + (size_t)l*MLP_*D_, fc1_b + l*MLP_, nullptr, gbf, nullptr, MLP_, D_);
    gemm_bt<3,64,4><<<dim3(D_/128, M_/64, 4), 256, 0, stream>>>(
        gbf, wfc2 + (size_t)l*D_*MLP_, fc2_b + l*D_, nullptr, nullptr, s, D_, MLP_);
  }
}

// Round 3
// 1016.994 us; speedup vs baseline: 1.0199x; 1.0039x over previous
//
#include <hip/hip_runtime.h>

#define B_    2
#define L_    1024
#define D_    768
#define H_    12
#define DH_   64
#define DP_   32
#define MLP_  3072
#define NL_   4
#define WIN_  128
#define W2_   257            // window columns (rel = j-i+128 in [0,256])
#define M_    (B_*L_)        // 2048 rows

typedef __attribute__((ext_vector_type(8))) short bf16x8;
typedef __attribute__((ext_vector_type(4))) float f32x4;

__device__ __forceinline__ unsigned short f2bf(float x){
  unsigned int u = __float_as_uint(x);
  u += 0x7fffu + ((u >> 16) & 1u);   // RNE; inputs finite
  return (unsigned short)(u >> 16);
}

__device__ __forceinline__ void gl_lds16(const void* g, void* l){
  __builtin_amdgcn_global_load_lds((__attribute__((address_space(1))) void*)g,
                                   (__attribute__((address_space(3))) void*)l, 16, 0, 0);
}

// ---------------- f32 -> bf16 weight conversion ----------------
__global__ __launch_bounds__(256) void cvt_bf16_k(const float* __restrict__ src,
                                                  unsigned short* __restrict__ dst, int n4){
  int i = blockIdx.x*256 + threadIdx.x;
  if (i >= n4) return;
  float4 v = ((const float4*)src)[i];
  ushort4 o;
  o.x = f2bf(v.x); o.y = f2bf(v.y); o.z = f2bf(v.z); o.w = f2bf(v.w);
  ((ushort4*)dst)[i] = o;
}

// ---------------- rope cos/sin table [L][32] (bit-identical ops to old rope_k) ----
__global__ __launch_bounds__(256) void rope_tab_k(float2* __restrict__ rtab){
  int idx = blockIdx.x*256 + threadIdx.x;     // 32768 entries
  int t = idx & 31, i = idx >> 5;
  float invf = expf(-(float)t * 0.28782313662425572f);   // ln(10000)/32
  float ang = (float)i * invf;
  float sn, cs;
  sincosf(ang, &sn, &cs);
  rtab[idx] = make_float2(cs, sn);
}

// ---------------- pair bias: LN(pair)@pb_w + pb_b for ALL layers, window only ----
__global__ __launch_bounds__(256) void pair_bias_k(const float* __restrict__ pair,
    const float* __restrict__ ln_g, const float* __restrict__ ln_b,
    const float* __restrict__ pb_w, const float* __restrict__ pb_b,
    float* __restrict__ bias){
  __shared__ float gw[NL_][DP_];
  __shared__ float cb[NL_];
  int tid = threadIdx.x;
  if (tid < NL_*DP_) gw[tid>>5][tid&31] = ln_g[tid]*pb_w[tid];
  if (tid < NL_){
    float c = 0.f;
    for (int d=0; d<DP_; ++d) c += ln_b[tid*DP_+d]*pb_w[tid*DP_+d];
    cb[tid] = c + pb_b[tid];
  }
  __syncthreads();
  int idx = blockIdx.x*256 + tid;
  if (idx >= B_*L_*W2_) return;
  int rel = idx % W2_;
  int t   = idx / W2_;
  int i   = t & (L_-1);
  int b   = t >> 10;
  int j   = i + rel - WIN_;
  if (j < 0 || j >= L_) return;            // never read by attention
  const float4* p = (const float4*)(pair + ((size_t)(b*L_ + i)*L_ + j)*DP_);
  float4 x[8];
  #pragma unroll
  for (int q=0;q<8;++q) x[q] = p[q];
  float s=0.f, ss=0.f;
  #pragma unroll
  for (int q=0;q<8;++q){
    s  += x[q].x + x[q].y + x[q].z + x[q].w;
    ss += x[q].x*x[q].x + x[q].y*x[q].y + x[q].z*x[q].z + x[q].w*x[q].w;
  }
  float m  = s * (1.0f/DP_);
  float rs = rsqrtf(ss*(1.0f/DP_) - m*m + 1e-5f);
  #pragma unroll
  for (int l=0;l<NL_;++l){
    float acc = 0.f;
    #pragma unroll
    for (int q=0;q<8;++q){
      acc += (x[q].x-m)*gw[l][4*q+0] + (x[q].y-m)*gw[l][4*q+1]
           + (x[q].z-m)*gw[l][4*q+2] + (x[q].w-m)*gw[l][4*q+3];
    }
    bias[(((size_t)l*B_ + b)*L_ + i)*W2_ + rel] = acc*rs + cb[l];
  }
}

// ---------------- rmsnorm: s[M,768] f32 -> h bf16 ----------------
__global__ __launch_bounds__(256) void rmsnorm_k(const float* __restrict__ s,
                                                 unsigned short* __restrict__ h){
  int row = blockIdx.x, tid = threadIdx.x;
  const float* x = s + (size_t)row*D_;
  float v0 = x[tid], v1 = x[tid+256], v2 = x[tid+512];
  float ss = v0*v0 + v1*v1 + v2*v2;
  #pragma unroll
  for (int m=1; m<64; m<<=1) ss += __shfl_xor(ss, m, 64);
  __shared__ float wsum[4];
  __shared__ float rbuf;
  if ((tid & 63) == 0) wsum[tid>>6] = ss;
  __syncthreads();
  if (tid == 0) rbuf = rsqrtf((wsum[0]+wsum[1]+wsum[2]+wsum[3])*(1.0f/D_) + 1.1920929e-07f);
  __syncthreads();
  float r = rbuf;
  unsigned short* o = h + (size_t)row*D_;
  o[tid]     = f2bf(v0*r);
  o[tid+256] = f2bf(v1*r);
  o[tid+512] = f2bf(v2*r);
}

// ---------------- bf16 GEMM: C[M,N] = A[M,K] @ W[N,K]^T + bias, fused epilogues ----
// MODE 0: qkv — q,k get RoPE applied in-register (partner col+32 is acc[mi][ni+2]),
//         written bf16 to outq/outk in [bh][i][64]; v cols -> outb bf16 [bh][j][64].
// MODE 1: resid += C          (attn out proj)
// MODE 2: outb = bf16(gelu(C))(fc1)
// MODE 3: resid += C          (fc2)
// TM: 128 or 64 (M rows per block). SPLIT: split-K factor (atomicAdd epilogue if >1).
template<int MODE, int TM, int SPLIT>
__global__ __launch_bounds__(256) void gemm_bt(const unsigned short* __restrict__ A,
    const unsigned short* __restrict__ W, const float* __restrict__ bias,
    unsigned short* __restrict__ outb, float* __restrict__ resid,
    unsigned short* __restrict__ outq, unsigned short* __restrict__ outk,
    const float2* __restrict__ rtab, int N, int K){
  constexpr int MI = TM/32;
  __shared__ __align__(16) short sm[2][(TM+128)*32];
  const int tid  = threadIdx.x;
  const int wave = tid >> 6, lane = tid & 63;
  const int m0 = blockIdx.y*TM, n0 = blockIdx.x << 7;
  const int KB = K / SPLIT;
  const int kbase = blockIdx.z * KB;
  const int wm = (wave >> 1)*(TM/2), wn = (wave & 1) << 6;
  const int lrow = lane & 15, ko = (lane >> 4) << 3;
  f32x4 acc[MI][4] = {};
  const unsigned short* Ag = A + (size_t)(m0 + (tid>>2))*K + kbase + ((tid&3)<<3);
  const unsigned short* Wg = W + (size_t)(n0 + (tid>>2))*K + kbase + ((tid&3)<<3);
  const size_t hstep = (size_t)64*K;
  const int nk = KB >> 5;
  {  // prologue stage into buf 0
    short* As = sm[0]; short* Bs = sm[0] + TM*32;
    gl_lds16(Ag, &As[tid*8]);
    if (TM == 128) gl_lds16(Ag + hstep, &As[(tid+256)*8]);
    gl_lds16(Wg, &Bs[tid*8]);
    gl_lds16(Wg + hstep, &Bs[(tid+256)*8]);
  }
  for (int it = 0; it < nk; ++it){
    __syncthreads();                       // drains vmcnt -> buf (it&1) ready
    if (it + 1 < nk){                      // async-prefetch next tile, overlaps MFMA below
      short* As = sm[(it&1)^1]; short* Bs = As + TM*32;
      const int kt = (it+1) << 5;
      gl_lds16(Ag + kt, &As[tid*8]);
      if (TM == 128) gl_lds16(Ag + hstep + kt, &As[(tid+256)*8]);
      gl_lds16(Wg + kt, &Bs[tid*8]);
      gl_lds16(Wg + hstep + kt, &Bs[(tid+256)*8]);
    }
    const short* As = sm[it&1]; const short* Bs = As + TM*32;
    bf16x8 af[MI], bv[4];
    #pragma unroll
    for (int i=0;i<MI;++i) af[i] = *(const bf16x8*)&As[((wm + i*16 + lrow) << 5) + ko];
    #pragma unroll
    for (int i=0;i<4;++i)  bv[i] = *(const bf16x8*)&Bs[((wn + i*16 + lrow) << 5) + ko];
    #pragma unroll
    for (int mi=0;mi<MI;++mi)
      #pragma unroll
      for (int ni=0;ni<4;++ni)
        acc[mi][ni] = __builtin_amdgcn_mfma_f32_16x16x32_bf16(af[mi], bv[ni], acc[mi][ni], 0, 0, 0);
  }
  if (MODE == 0){
    // rope-fused epilogue: process (ni, ni+2) pairs = (d, d+32) of one head
    #pragma unroll
    for (int ni=0; ni<2; ++ni){
      const int col0 = n0 + wn + ni*16 + lrow;       // d = d0 in [0,32)
      const int d0 = ni*16 + lrow;
      const float b0 = bias[col0], b2 = bias[col0 + 32];
      #pragma unroll
      for (int mi=0; mi<MI; ++mi){
        const int rw = m0 + wm + mi*16 + ((lane >> 4) << 2);
        #pragma unroll
        for (int r=0; r<4; ++r){
          const int rowg = rw + r;
          const int bI = rowg >> 10, iI = rowg & (L_-1);
          const float v0 = acc[mi][ni][r]   + b0;
          const float v2 = acc[mi][ni+2][r] + b2;
          if (col0 < 2*D_){
            const bool isq = (col0 < D_);
            const int  h   = (isq ? col0 : col0 - D_) >> 6;
            const float2 cssn = rtab[iI*32 + d0];
            const float o0 = v0*cssn.x - v2*cssn.y;   // d<32: q*c - q[d+32]*s
            const float o2 = v2*cssn.x + v0*cssn.y;   // d>=32: q*c + q[d-32]*s
            unsigned short* dst = (isq ? outq : outk)
                + ((((size_t)(bI*H_ + h)) << 10 | iI) << 6);
            dst[d0]      = f2bf(o0);
            dst[d0 + 32] = f2bf(o2);
          } else {
            const int h = (col0 - 2*D_) >> 6;
            unsigned short* dst = outb + ((((size_t)(bI*H_ + h)) << 10 | iI) << 6);
            dst[d0]      = f2bf(v0);
            dst[d0 + 32] = f2bf(v2);
          }
        }
      }
    }
  } else {
    #pragma unroll
    for (int ni=0;ni<4;++ni){
      const int col = n0 + wn + ni*16 + lrow;
      const float bb = (SPLIT == 1 || blockIdx.z == 0) ? bias[col] : 0.f;
      #pragma unroll
      for (int mi=0;mi<MI;++mi){
        const int rw = m0 + wm + mi*16 + ((lane >> 4) << 2);
        #pragma unroll
        for (int r=0;r<4;++r){
          float v = acc[mi][ni][r] + bb;
          if (MODE == 2){
            float g = 0.5f * v * (1.0f + erff(v * 0.70710678118654752f));
            outb[(size_t)(rw + r)*N + col] = f2bf(g);
          } else {
            if (SPLIT == 1) resid[(size_t)(rw + r)*D_ + col] += v;
            else            atomicAdd(&resid[(size_t)(rw + r)*D_ + col], v);
          }
        }
      }
    }
  }
}

// ---------------- windowed MFMA attention, 32-query tiles ----------------
// Per block: one (bh, 32-query tile). K-strip of 288 keys staged bf16 in LDS
// (precomputed bf16 K, no conversion), QK^T and PV via 16x16x32 bf16 MFMA.
// V (precomputed bf16) reuses the K buffer after softmax.
__global__ __launch_bounds__(256) void attn_k(const unsigned short* __restrict__ qr,
    const unsigned short* __restrict__ kr, const unsigned short* __restrict__ vr,
    const float* __restrict__ bias, unsigned short* __restrict__ ybf, int layer){
  __shared__ __align__(16) short kb[288*72];   // K then V, row stride 72 (+8 pad) = 41472 B
  __shared__ __align__(16) float sc[32*304];   // scores f32; probs bf16 alias below
  short* ps = (short*)sc;                      // [32][296] bf16 (stride 296: conflict-free b128)
  const int tid  = threadIdx.x;
  const int wave = tid >> 6, lane = tid & 63;
  const int quad = lane >> 4, lrow = lane & 15;
  const int bh = blockIdx.y, b = bh / H_, h = bh - b*H_;
  const int i0 = blockIdx.x * 32, jb = i0 - WIN_;

  // Q fragments for both 16-row m-tiles: A[m=lrow][k=quad*8+j], two K=32 halves
  bf16x8 qf[2][2];
  #pragma unroll
  for (int mt=0; mt<2; ++mt){
    const unsigned short* qrow = qr + (((size_t)bh*L_ + i0 + mt*16 + lrow) << 6) + quad*8;
    qf[mt][0] = *(const bf16x8*)qrow;
    qf[mt][1] = *(const bf16x8*)(qrow + 32);
  }
  // stage K strip (288 rows x 64 bf16), zero-filled outside [0,L)
  {
    const int r0 = tid >> 3, seg = tid & 7;
    #pragma unroll
    for (int p=0; p<9; ++p){
      const int r = r0 + p*32;
      const int jg = jb + r;
      bf16x8 z;
      #pragma unroll
      for (int q=0;q<8;++q) z[q] = 0;
      if ((unsigned)jg < L_) z = *(const bf16x8*)(kr + (((size_t)bh*L_ + jg) << 6) + seg*8);
      *(bf16x8*)&kb[r*72 + seg*8] = z;
    }
  }
  __syncthreads();
  // QK^T: 18 key-chunks of 16, round-robin over waves; each wave does both m-tiles
  for (int c = wave; c < 18; c += 4){
    const int krow = c*16 + lrow;
    const bf16x8 kf0 = *(const bf16x8*)&kb[krow*72 + quad*8];
    const bf16x8 kf1 = *(const bf16x8*)&kb[krow*72 + 32 + quad*8];
    const int jj = c*16 + lrow, jg = jb + jj;
    #pragma unroll
    for (int mt=0; mt<2; ++mt){
      f32x4 cc = {0.f,0.f,0.f,0.f};
      cc = __builtin_amdgcn_mfma_f32_16x16x32_bf16(qf[mt][0], kf0, cc, 0, 0, 0);
      cc = __builtin_amdgcn_mfma_f32_16x16x32_bf16(qf[mt][1], kf1, cc, 0, 0, 0);
      #pragma unroll
      for (int r=0;r<4;++r){
        const int row = mt*16 + quad*4 + r;
        const int rel = jj - row;             // j - i + 128
        float v = -1e30f;
        if (rel >= 0 && rel <= 256 && (unsigned)jg < L_)
          v = cc[r]*0.125f + bias[(((size_t)(layer*B_ + b))*L_ + i0 + row)*W2_ + rel];
        sc[row*304 + jj] = v;
      }
    }
  }
  __syncthreads();
  // softmax: thread group of 16 handles rows qq and qq+16
  const int qq = tid >> 4, tj = tid & 15;
  float ev[2][18];
  #pragma unroll
  for (int g=0; g<2; ++g)
    #pragma unroll
    for (int c=0;c<18;++c) ev[g][c] = sc[(qq + g*16)*304 + c*16 + tj];
  __syncthreads();                 // all sc reads done before ps alias-writes
  #pragma unroll
  for (int g=0; g<2; ++g){
    float mx = -3.0e38f;
    #pragma unroll
    for (int c=0;c<18;++c) mx = fmaxf(mx, ev[g][c]);
    #pragma unroll
    for (int m=1; m<16; m<<=1) mx = fmaxf(mx, __shfl_xor(mx, m, 16));
    float sm = 0.f;
    #pragma unroll
    for (int c=0;c<18;++c){ float e = __expf(ev[g][c] - mx); ev[g][c] = e; sm += e; }
    #pragma unroll
    for (int m=1; m<16; m<<=1) sm += __shfl_xor(sm, m, 16);
    const float inv = 1.0f / sm;
    #pragma unroll
    for (int c=0;c<18;++c) ps[(qq + g*16)*296 + c*16 + tj] = (short)f2bf(ev[g][c]*inv);
  }
  // stage V into kb (zero-fill: ps~0 rows must not meet inf/NaN)
  {
    const int r0 = tid >> 3, seg = tid & 7;
    #pragma unroll
    for (int p=0; p<9; ++p){
      const int r = r0 + p*32;
      const int jg = jb + r;
      bf16x8 z;
      #pragma unroll
      for (int q=0;q<8;++q) z[q] = 0;
      if ((unsigned)jg < L_) z = *(const bf16x8*)(vr + (((size_t)bh*L_ + jg) << 6) + seg*8);
      *(bf16x8*)&kb[r*72 + seg*8] = z;
    }
  }
  __syncthreads();
  // PV: O[32][64] = P[32x288] @ V[288x64]; wave owns d-tile [wave*16, wave*16+16)
  f32x4 o0 = {0.f,0.f,0.f,0.f}, o1 = {0.f,0.f,0.f,0.f};
  for (int kc=0; kc<9; ++kc){
    bf16x8 bf;
    #pragma unroll
    for (int j=0;j<8;++j) bf[j] = kb[(kc*32 + quad*8 + j)*72 + wave*16 + lrow];
    const bf16x8 a0 = *(const bf16x8*)&ps[lrow*296 + kc*32 + quad*8];
    const bf16x8 a1 = *(const bf16x8*)&ps[(16 + lrow)*296 + kc*32 + quad*8];
    o0 = __builtin_amdgcn_mfma_f32_16x16x32_bf16(a0, bf, o0, 0, 0, 0);
    o1 = __builtin_amdgcn_mfma_f32_16x16x32_bf16(a1, bf, o1, 0, 0, 0);
  }
  #pragma unroll
  for (int r=0;r<4;++r){
    const int row = quad*4 + r;
    ybf[((size_t)(b*L_ + i0 + row))*D_ + h*64 + wave*16 + lrow]      = f2bf(o0[r]);
    ybf[((size_t)(b*L_ + i0 + 16 + row))*D_ + h*64 + wave*16 + lrow] = f2bf(o1[r]);
  }
}

extern "C" void kernel_launch(void* const* d_in, const int* in_sizes, int n_in,
                              void* d_out, int out_size, void* d_ws, size_t ws_size,
                              hipStream_t stream){
  (void)in_sizes; (void)n_in; (void)out_size; (void)ws_size;
  const float* s_in  = (const float*)d_in[0];
  const float* pair  = (const float*)d_in[1];
  const float* qkv_w = (const float*)d_in[2];
  const float* qkv_b = (const float*)d_in[3];
  const float* out_w = (const float*)d_in[4];
  const float* out_b = (const float*)d_in[5];
  const float* fc1_w = (const float*)d_in[6];
  const float* fc1_b = (const float*)d_in[7];
  const float* fc2_w = (const float*)d_in[8];
  const float* fc2_b = (const float*)d_in[9];
  const float* ln_g  = (const float*)d_in[10];
  const float* ln_b  = (const float*)d_in[11];
  const float* pb_w  = (const float*)d_in[12];
  const float* pb_b  = (const float*)d_in[13];
  float* s = (float*)d_out;                    // residual stream lives in d_out

  char* ws = (char*)d_ws;
  size_t off = 0;
  auto take = [&](size_t bytes)->char*{
    char* p = ws + off; off += (bytes + 255) & ~(size_t)255; return p;
  };
  unsigned short* wqkv = (unsigned short*)take((size_t)NL_*3*D_*D_*2);
  unsigned short* wout = (unsigned short*)take((size_t)NL_*D_*D_*2);
  unsigned short* wfc1 = (unsigned short*)take((size_t)NL_*MLP_*D_*2);
  unsigned short* wfc2 = (unsigned short*)take((size_t)NL_*D_*MLP_*2);
  float*          bw   = (float*)take((size_t)NL_*B_*L_*W2_*4);
  unsigned short* hbf  = (unsigned short*)take((size_t)M_*D_*2);
  unsigned short* qrb  = (unsigned short*)take((size_t)B_*H_*L_*DH_*2);
  unsigned short* krb  = (unsigned short*)take((size_t)B_*H_*L_*DH_*2);
  unsigned short* vrb  = (unsigned short*)take((size_t)B_*H_*L_*DH_*2);
  unsigned short* ybf  = (unsigned short*)take((size_t)M_*D_*2);
  unsigned short* gbf  = (unsigned short*)take((size_t)M_*MLP_*2);
  float2*         rtab = (float2*)take((size_t)L_*32*sizeof(float2));

  hipMemcpyAsync(s, s_in, (size_t)M_*D_*sizeof(float), hipMemcpyDeviceToDevice, stream);

  auto cvt = [&](const float* src, unsigned short* dst, size_t n){
    int n4 = (int)(n/4);
    cvt_bf16_k<<<(n4+255)/256, 256, 0, stream>>>(src, dst, n4);
  };
  cvt(qkv_w, wqkv, (size_t)NL_*3*D_*D_);
  cvt(out_w, wout, (size_t)NL_*D_*D_);
  cvt(fc1_w, wfc1, (size_t)NL_*MLP_*D_);
  cvt(fc2_w, wfc2, (size_t)NL_*D_*MLP_);

  rope_tab_k<<<(L_*32)/256, 256, 0, stream>>>(rtab);
  pair_bias_k<<<(B_*L_*W2_ + 255)/256, 256, 0, stream>>>(pair, ln_g, ln_b, pb_w, pb_b, bw);

  for (int l=0; l<NL_; ++l){
    rmsnorm_k<<<M_, 256, 0, stream>>>(s, hbf);
    gemm_bt<0,128,1><<<dim3((3*D_)/128, M_/128), 256, 0, stream>>>(
        hbf, wqkv + (size_t)l*3*D_*D_, qkv_b + l*3*D_, vrb, nullptr, qrb, krb, rtab, 3*D_, D_);
    attn_k<<<dim3(L_/32, B_*H_), 256, 0, stream>>>(qrb, krb, vrb, bw, ybf, l);
    gemm_bt<1,64,2><<<dim3(D_/128, M_/64, 2), 256, 0, stream>>>(
        ybf, wout + (size_t)l*D_*D_, out_b + l*D_, nullptr, s, nullptr, nullptr, nullptr, D_, D_);
    rmsnorm_k<<<M_, 256, 0, stream>>>(s, hbf);
    gemm_bt<2,128,1><<<dim3(MLP_/128, M_/128), 256, 0, stream>>>(
        hbf, wfc1 + (size_t)l*MLP_*D_, fc1_b + l*MLP_, gbf, nullptr, nullptr, nullptr, nullptr, MLP_, D_);
    gemm_bt<3,64,4><<<dim3(D_/128, M_/64, 4), 256, 0, stream>>>(
        gbf, wfc2 + (size_t)l*D_*MLP_, fc2_b + l*D_, nullptr, s, nullptr, nullptr, nullptr, D_, MLP_);
  }
}